// Round 3
// baseline (597.140 us; speedup 1.0000x reference)
//
#include <hip/hip_runtime.h>
#include <stdint.h>

#define B_  8
#define S1_ 2048
#define S2_ 2048
#define H_  1024

typedef __attribute__((ext_vector_type(8))) short bf16x8;
typedef __attribute__((ext_vector_type(4))) float f32x4;
typedef unsigned short u16;

__device__ __forceinline__ float bf2f(u16 u){
  union { float f; uint32_t v; } x; x.v = ((uint32_t)u) << 16; return x.f;
}
__device__ __forceinline__ u16 f2bf(float f){
  union { float f; uint32_t v; } x; x.f = f;
  uint32_t r = x.v + 0x7fffu + ((x.v >> 16) & 1u);
  return (u16)(r >> 16);
}
__device__ __forceinline__ u16 f2h(float f){
  union { _Float16 h; u16 u; } c; c.h = (_Float16)f; return c.u;
}
__device__ __forceinline__ float h2f(u16 u){
  union { _Float16 h; u16 u; } c; c.u = u; return (float)c.h;
}
__device__ __forceinline__ void async16(void* lds, const void* g){
  __builtin_amdgcn_global_load_lds(
      (const __attribute__((address_space(1))) uint32_t*)g,
      (__attribute__((address_space(3))) uint32_t*)lds, 16, 0, 0);
}

// ---------------- fp32 -> bf16 copy ----------------
__global__ __launch_bounds__(256) void k_cvt_bf16(const float* __restrict__ in,
                                                  u16* __restrict__ out, long n){
  long i = ((long)blockIdx.x * 256 + threadIdx.x) * 8;
  const long stride = (long)gridDim.x * 256 * 8;
  for (; i < n; i += stride){
    float4 a = *(const float4*)(in + i);
    float4 b = *(const float4*)(in + i + 4);
    bf16x8 o;
    o[0]=(short)f2bf(a.x); o[1]=(short)f2bf(a.y); o[2]=(short)f2bf(a.z); o[3]=(short)f2bf(a.w);
    o[4]=(short)f2bf(b.x); o[5]=(short)f2bf(b.y); o[6]=(short)f2bf(b.z); o[7]=(short)f2bf(b.w);
    *(bf16x8*)(out + i) = o;
  }
}

// ---------------- W (fp32) transpose -> bf16 ----------------
__global__ __launch_bounds__(256) void k_transpose_w(const float* __restrict__ W,
                                                     u16* __restrict__ WT){
  __shared__ u16 t[32][33];
  const int x = threadIdx.x & 31, y0 = threadIdx.x >> 5;
  const int bx = blockIdx.x * 32, by = blockIdx.y * 32;
  for (int r = y0; r < 32; r += 8) t[r][x] = f2bf(W[(by + r) * H_ + bx + x]);
  __syncthreads();
  for (int r = y0; r < 32; r += 8) WT[(bx + r) * H_ + by + x] = t[x][r];
}

// ------- C = A @ B^T  (A[M][K], B[N][K], bf16) ; OM: 0 -> bf16 C, 1 -> fp16 C -------
template<int OM>
__global__ __launch_bounds__(256) void k_gemm_bt(
    const u16* __restrict__ A, const u16* __restrict__ Bm, u16* __restrict__ C,
    int M, int N, int K, long sA, long sB, long sC)
{
  A += (long)blockIdx.z * sA; Bm += (long)blockIdx.z * sB; C += (long)blockIdx.z * sC;
  __shared__ u16 As[128*32];
  __shared__ u16 Bs[128*32];
  const int tid = threadIdx.x, lane = tid & 63, w = tid >> 6;
  const int wr = (w >> 1) * 64, wc = (w & 1) * 64;
  const int brow = blockIdx.x * 128, bcol = blockIdx.y * 128;
  f32x4 acc[4][4];
#pragma unroll
  for (int m=0;m<4;++m)
#pragma unroll
    for (int n=0;n<4;++n) acc[m][n] = (f32x4){0.f,0.f,0.f,0.f};

  const int srow = w*16 + (lane >> 2);
  const int scol = (lane & 3) * 8;
  const u16* ga = A + (long)(brow + srow) * K + scol;
  const u16* gb = Bm + (long)(bcol + srow) * K + scol;
  u16* lA0 = As + (w*16)*32;  u16* lA1 = As + (64 + w*16)*32;
  u16* lB0 = Bs + (w*16)*32;  u16* lB1 = Bs + (64 + w*16)*32;

  const int koff = (lane >> 4) * 8;
  const int fr = lane & 15;

  for (int k0 = 0; k0 < K; k0 += 32){
    async16(lA0, ga);  async16(lA1, ga + (long)64*K);
    async16(lB0, gb);  async16(lB1, gb + (long)64*K);
    ga += 32; gb += 32;
    __syncthreads();
    bf16x8 af[4], bf[4];
#pragma unroll
    for (int m=0;m<4;++m) af[m] = *(const bf16x8*)(As + (wr + m*16 + fr)*32 + koff);
#pragma unroll
    for (int n=0;n<4;++n) bf[n] = *(const bf16x8*)(Bs + (wc + n*16 + fr)*32 + koff);
#pragma unroll
    for (int m=0;m<4;++m)
#pragma unroll
      for (int n=0;n<4;++n)
        acc[m][n] = __builtin_amdgcn_mfma_f32_16x16x32_bf16(af[m], bf[n], acc[m][n], 0,0,0);
    __syncthreads();
  }
  const int crow = brow + wr + (lane >> 4) * 4;
  const int ccol = bcol + wc + fr;
#pragma unroll
  for (int m=0;m<4;++m)
#pragma unroll
    for (int n=0;n<4;++n){
      f32x4 v = acc[m][n];
      u16* cp = C + (long)(crow + m*16) * N + ccol + n*16;
#pragma unroll
      for (int q=0;q<4;++q) cp[(long)q*N] = OM ? f2h(v[q]) : f2bf(v[q]);
    }
}

// ---------------- row stats over fp16 scores ----------------
__global__ __launch_bounds__(256) void k_row_stats(const u16* __restrict__ Wg,
                                                   float* __restrict__ rmax,
                                                   float* __restrict__ rinv){
  const long row = blockIdx.x;               // B*S1 rows
  const u16* p = Wg + row * S2_;
  const int tid = threadIdx.x, lane = tid & 63, w = tid >> 6;
  bf16x8 v = *(const bf16x8*)(p + tid*8);
  float x[8]; float m = -3.4e38f;
#pragma unroll
  for (int j=0;j<8;++j){ x[j] = h2f((u16)v[j]); m = fmaxf(m, x[j]); }
#pragma unroll
  for (int off=1; off<64; off<<=1) m = fmaxf(m, __shfl_xor(m, off));
  __shared__ float sm[4], ss[4];
  if (lane == 0) sm[w] = m;
  __syncthreads();
  m = fmaxf(fmaxf(sm[0],sm[1]), fmaxf(sm[2],sm[3]));
  float s = 0.f;
#pragma unroll
  for (int j=0;j<8;++j) s += __expf(x[j] - m);
#pragma unroll
  for (int off=1; off<64; off<<=1) s += __shfl_xor(s, off);
  if (lane == 0) ss[w] = s;
  __syncthreads();
  if (tid == 0){
    float t = ss[0]+ss[1]+ss[2]+ss[3];
    rmax[row] = m; rinv[row] = 1.f / t;
  }
}

// ---------------- col stats over fp16 scores ----------------
__global__ __launch_bounds__(512) void k_col_stats(const u16* __restrict__ Wg,
                                                   float* __restrict__ cmax,
                                                   float* __restrict__ cinv){
  const int b = blockIdx.y;
  const int j0 = blockIdx.x * 64;
  const int jj = threadIdx.x & 63, ic = threadIdx.x >> 6;   // 8 i-chunks
  const u16* p = Wg + (long)b*S1_*S2_ + j0 + jj;
  float m = -3.4e38f;
  for (int i = ic*256; i < ic*256 + 256; ++i) m = fmaxf(m, h2f(p[(long)i * S2_]));
  __shared__ float red[8][64];
  red[ic][jj] = m;
  __syncthreads();
  if (ic == 0){
#pragma unroll
    for (int r=1;r<8;++r) m = fmaxf(m, red[r][jj]);
    red[0][jj] = m;
  }
  __syncthreads();
  m = red[0][jj];
  float s = 0.f;
  for (int i = ic*256; i < ic*256 + 256; ++i) s += __expf(h2f(p[(long)i*S2_]) - m);
  __shared__ float red2[8][64];
  red2[ic][jj] = s;
  __syncthreads();
  if (ic == 0){
#pragma unroll
    for (int r=1;r<8;++r) s += red2[r][jj];
    cmax[b*S2_ + j0 + jj] = m;
    cinv[b*S2_ + j0 + jj] = 1.f / s;
  }
}

// -------- hidden_2 = softmax_rows(scores) @ h2b : fused row-softmax NN GEMM --------
// M=S1 (i), N=H, K=S2 (j). A staged from fp16 scores with exp transform; fp32 C.
__global__ __launch_bounds__(256) void k_gemm_h2(
    const u16* __restrict__ Wg, const u16* __restrict__ Bm, float* __restrict__ C,
    const float* __restrict__ rmax, const float* __restrict__ rinv)
{
  const int b = blockIdx.z;
  const u16* A  = Wg + (long)b * S1_ * S2_;
  const u16* Bp = Bm + (long)b * S2_ * H_;
  float* Cp = C + (long)b * S1_ * H_;

  __shared__ u16 As[128*32];
  __shared__ u16 Bs[32*128];
  const int tid = threadIdx.x, lane = tid & 63, w = tid >> 6;
  const int wr = (w >> 1) * 64, wc = (w & 1) * 64;
  const int brow = blockIdx.x * 128, bcol = blockIdx.y * 128;
  f32x4 acc[4][4];
#pragma unroll
  for (int m=0;m<4;++m)
#pragma unroll
    for (int n=0;n<4;++n) acc[m][n] = (f32x4){0.f,0.f,0.f,0.f};

  const int arow = w*16 + (lane >> 2);
  const int scol = (lane & 3) * 8;
  const u16* gA0 = A + (long)(brow + arow) * S2_ + scol;
  const u16* gA1 = gA0 + (long)64 * S2_;
  const float rm0 = rmax[b*S1_ + brow + arow],      ri0 = rinv[b*S1_ + brow + arow];
  const float rm1 = rmax[b*S1_ + brow + arow + 64], ri1 = rinv[b*S1_ + brow + arow + 64];
  u16* wA0 = As + arow*32 + scol;
  u16* wA1 = As + (arow+64)*32 + scol;

  // B staging: async16 with chunk-XOR swizzle (pre-swizzled global source)
  const int Rr  = w*4 + (lane >> 4);
  const int m15 = lane & 15;
  const int c0 = ((m15 ^ ((( Rr     >> 3) & 3) << 1)) << 3);
  const int c1 = ((m15 ^ ((((Rr+16) >> 3) & 3) << 1)) << 3);
  const u16* gB = Bp + (long)Rr * H_ + bcol;
  u16* lB0 = Bs + (w*4)*128;  u16* lB1 = Bs + (16 + w*4)*128;

  const int koff = (lane >> 4) * 8;
  const int fr = m15;
  const int hi2 = (lane >> 4) << 1;
  int scb[4];
#pragma unroll
  for (int n=0;n<4;++n){
    int cb = wc + n*16 + fr;
    scb[n] = (((cb >> 3) ^ hi2) << 3) | (cb & 7);
  }

  for (int k0 = 0; k0 < S2_; k0 += 32){
    bf16x8 x0 = *(const bf16x8*)(gA0 + k0);
    bf16x8 x1 = *(const bf16x8*)(gA1 + k0);
    async16(lB0, gB + c0);  async16(lB1, gB + (long)16*H_ + c1);
    gB += (long)32*H_;
    bf16x8 y0, y1;
#pragma unroll
    for (int q=0;q<8;++q){
      y0[q] = (short)f2bf(__expf(h2f((u16)x0[q]) - rm0) * ri0);
      y1[q] = (short)f2bf(__expf(h2f((u16)x1[q]) - rm1) * ri1);
    }
    *(bf16x8*)wA0 = y0;
    *(bf16x8*)wA1 = y1;
    __syncthreads();
    bf16x8 af[4], bf[4];
#pragma unroll
    for (int m=0;m<4;++m) af[m] = *(const bf16x8*)(As + (wr + m*16 + fr)*32 + koff);
#pragma unroll
    for (int n=0;n<4;++n){
      bf16x8 bb;
#pragma unroll
      for (int j=0;j<8;++j) bb[j] = (short)Bs[(koff + j)*128 + scb[n]];
      bf[n] = bb;
    }
#pragma unroll
    for (int m=0;m<4;++m)
#pragma unroll
      for (int n=0;n<4;++n)
        acc[m][n] = __builtin_amdgcn_mfma_f32_16x16x32_bf16(af[m], bf[n], acc[m][n], 0,0,0);
    __syncthreads();
  }
  const int crow = brow + wr + (lane >> 4) * 4;
  const int ccol = bcol + wc + fr;
#pragma unroll
  for (int m=0;m<4;++m)
#pragma unroll
    for (int n=0;n<4;++n){
      f32x4 v = acc[m][n];
      float* cp = Cp + (long)(crow + m*16) * H_ + ccol + n*16;
#pragma unroll
      for (int q=0;q<4;++q) cp[(long)q*H_] = v[q];
    }
}

// -------- hidden_1 = softmax_cols(scores)^T @ h1b : fused col-softmax NN GEMM --------
// M=S2 (j), N=H, K=S1 (i). A'[j][i] = exp(s[i][j]-cmax[j])*cinv[j]; fp32 C.
__global__ __launch_bounds__(256) void k_gemm_h1(
    const u16* __restrict__ Wg, const u16* __restrict__ Bm, float* __restrict__ C,
    const float* __restrict__ cmax, const float* __restrict__ cinv)
{
  const int b = blockIdx.z;
  const u16* A  = Wg + (long)b * S1_ * S2_;
  const u16* Bp = Bm + (long)b * S1_ * H_;
  float* Cp = C + (long)b * S2_ * H_;

  __shared__ u16 As[128*32];     // [j_local][i_local]
  __shared__ u16 Bs[32*128];
  const int tid = threadIdx.x, lane = tid & 63, w = tid >> 6;
  const int wr = (w >> 1) * 64, wc = (w & 1) * 64;
  const int brow = blockIdx.x * 128, bcol = blockIdx.y * 128;
  f32x4 acc[4][4];
#pragma unroll
  for (int m=0;m<4;++m)
#pragma unroll
    for (int n=0;n<4;++n) acc[m][n] = (f32x4){0.f,0.f,0.f,0.f};

  const int ia = lane & 15;
  const int j0 = (w*4 + (lane >> 4)) * 8;
  float cm[8], ci[8];
#pragma unroll
  for (int q=0;q<8;++q){
    cm[q] = cmax[b*S2_ + brow + j0 + q];
    ci[q] = cinv[b*S2_ + brow + j0 + q];
  }
  const u16* gA = A + brow + j0;     // + i_g * S2_

  const int Rr  = w*4 + (lane >> 4);
  const int m15 = lane & 15;
  const int c0 = ((m15 ^ ((( Rr     >> 3) & 3) << 1)) << 3);
  const int c1 = ((m15 ^ ((((Rr+16) >> 3) & 3) << 1)) << 3);
  const u16* gB = Bp + (long)Rr * H_ + bcol;
  u16* lB0 = Bs + (w*4)*128;  u16* lB1 = Bs + (16 + w*4)*128;

  const int koff = (lane >> 4) * 8;
  const int fr = m15;
  const int hi2 = (lane >> 4) << 1;
  int scb[4];
#pragma unroll
  for (int n=0;n<4;++n){
    int cb = wc + n*16 + fr;
    scb[n] = (((cb >> 3) ^ hi2) << 3) | (cb & 7);
  }

  for (int k0 = 0; k0 < S1_; k0 += 32){
    bf16x8 x0 = *(const bf16x8*)(gA + (long)(k0 + ia) * S2_);
    bf16x8 x1 = *(const bf16x8*)(gA + (long)(k0 + 16 + ia) * S2_);
    async16(lB0, gB + c0);  async16(lB1, gB + (long)16*H_ + c1);
    gB += (long)32*H_;
#pragma unroll
    for (int q=0;q<8;++q){
      As[(j0+q)*32 + ia]      = f2bf(__expf(h2f((u16)x0[q]) - cm[q]) * ci[q]);
      As[(j0+q)*32 + 16 + ia] = f2bf(__expf(h2f((u16)x1[q]) - cm[q]) * ci[q]);
    }
    __syncthreads();
    bf16x8 af[4], bf[4];
#pragma unroll
    for (int m=0;m<4;++m) af[m] = *(const bf16x8*)(As + (wr + m*16 + fr)*32 + koff);
#pragma unroll
    for (int n=0;n<4;++n){
      bf16x8 bb;
#pragma unroll
      for (int j=0;j<8;++j) bb[j] = (short)Bs[(koff + j)*128 + scb[n]];
      bf[n] = bb;
    }
#pragma unroll
    for (int m=0;m<4;++m)
#pragma unroll
      for (int n=0;n<4;++n)
        acc[m][n] = __builtin_amdgcn_mfma_f32_16x16x32_bf16(af[m], bf[n], acc[m][n], 0,0,0);
    __syncthreads();
  }
  const int crow = brow + wr + (lane >> 4) * 4;
  const int ccol = bcol + wc + fr;
#pragma unroll
  for (int m=0;m<4;++m)
#pragma unroll
    for (int n=0;n<4;++n){
      f32x4 v = acc[m][n];
      float* cp = Cp + (long)(crow + m*16) * H_ + ccol + n*16;
#pragma unroll
      for (int q=0;q<4;++q) cp[(long)q*H_] = v[q];
    }
}

extern "C" void kernel_launch(void* const* d_in, const int* in_sizes, int n_in,
                              void* d_out, int out_size, void* d_ws, size_t ws_size,
                              hipStream_t stream)
{
  const float* h1 = (const float*)d_in[0];   // hidden1 (B,S1,H) fp32
  const float* h2 = (const float*)d_in[1];   // hidden2 (B,S2,H) fp32
  const float* W  = (const float*)d_in[2];   // W (H,H) fp32
  // bias (d_in[3]): uniform shift of scores -> softmax-invariant: unused.
  float* out0 = (float*)d_out;                        // hidden_1 (B,S2,H) fp32
  float* out1 = out0 + (size_t)B_ * S2_ * H_;         // hidden_2 (B,S1,H) fp32

  const long NE = (long)B_ * S1_ * H_;   // 16.78M elems per hidden tensor

  // ws layout (~100.9 MiB): stats, fp16 scores (WTb overlaps its start), h2b.
  char* ws = (char*)d_ws;
  size_t off = 0;
  float* rmax = (float*)(ws + off); off += (size_t)B_*S1_*4;
  float* rinv = (float*)(ws + off); off += (size_t)B_*S1_*4;
  float* cmax = (float*)(ws + off); off += (size_t)B_*S2_*4;
  float* cinv = (float*)(ws + off); off += (size_t)B_*S2_*4;
  u16* Wg  = (u16*)(ws + off);                       // fp16 scores, 67.1 MB
  u16* WTb = Wg;                                     // bf16 W^T, dead before Wg written
  off += (size_t)B_*S1_*S2_*2;
  u16* h2b = (u16*)(ws + off); off += (size_t)NE*2;  // bf16 h2, 33.55 MB

  // out1 scratch: Qb (first half) + h1b (second half); both dead before
  // k_gemm_h2 writes out1. out0 untouched until k_gemm_h1 writes it.
  u16* Qb  = (u16*)out1;
  u16* h1b = (u16*)out1 + NE;

  k_cvt_bf16<<<dim3(4096), 256, 0, stream>>>(h1, h1b, NE);
  k_cvt_bf16<<<dim3(4096), 256, 0, stream>>>(h2, h2b, NE);
  k_transpose_w<<<dim3(32,32), 256, 0, stream>>>(W, WTb);
  // Q = h1 @ W = h1b @ WTb^T  (M=S1,N=H,K=H) -> bf16
  k_gemm_bt<0><<<dim3(16, 8, 8), 256, 0, stream>>>(h1b, WTb, Qb, S1_, H_, H_,
        (long)S1_*H_, 0L, (long)S1_*H_);
  // scores = Q @ h2^T  (M=S1,N=S2,K=H) -> fp16
  k_gemm_bt<1><<<dim3(16,16,8), 256, 0, stream>>>(Qb, h2b, Wg, S1_, S2_, H_,
        (long)S1_*H_, (long)S2_*H_, (long)S1_*S2_);
  k_row_stats<<<dim3(B_*S1_), 256, 0, stream>>>(Wg, rmax, rinv);
  k_col_stats<<<dim3(S2_/64, B_), 512, 0, stream>>>(Wg, cmax, cinv);
  // hidden_1 = softmax_cols(scores)^T @ h1b -> out0 (fp32)
  k_gemm_h1<<<dim3(16, 8, 8), 256, 0, stream>>>(Wg, h1b, out0, cmax, cinv);
  // hidden_2 = softmax_rows(scores) @ h2b -> out1 (fp32, overwrites Qb/h1b)
  k_gemm_h2<<<dim3(16, 8, 8), 256, 0, stream>>>(Wg, h2b, out1, rmax, rinv);
}